// Round 1
// baseline (488.387 us; speedup 1.0000x reference)
//
#include <hip/hip_runtime.h>

// FlexAttention: sliding-window causal attention + per-head sink logit.
// B=2, H=16, S=2048, D=64, window=1024. fp32 flash-attention baseline.
//
// Design (R1, correctness + baseline):
//  - grid = (S/64 q-tiles, B*H). block = 256 threads = 4 waves.
//  - thread t: lq = t&63 (query in tile), g = t>>6 (wave id).
//    Wave g computes scores for keys [16g,16g+16) of the K-tile and
//    accumulates output dims [16g,16g+16) for its query.
//  - Q row (64 fp32) in registers; K/V 64x64 tiles staged in LDS
//    (K/V LDS reads are wave-uniform broadcasts).
//  - online softmax with sink: init m = sink_w[h], l = 1 (sink value = 0,
//    so it only adds exp(sink-m) to the denominator) -> exact equivalence
//    with the reference's appended sink column.
//  - probs round-trip through p_lds[64][65] (stride 65 -> 2-way bank
//    aliasing only, which is free on CDNA4).

#define TQ 64
#define TK 64
#define DD 64
#define NT 256

__global__ __launch_bounds__(NT, 2) void flex_attn_fp32(
    const float* __restrict__ Q, const float* __restrict__ K,
    const float* __restrict__ V, const float* __restrict__ SINKW,
    const int* __restrict__ SWIN, float* __restrict__ OUT,
    const int H, const int S)
{
    const int t  = threadIdx.x;
    const int lq = t & 63;       // query within tile
    const int g  = t >> 6;       // wave id: key-group (scores) / dim-group (acc)
    const int qt = blockIdx.x;
    const int bh = blockIdx.y;
    const int h  = bh % H;
    const int q0 = qt * TQ;
    const int qi = q0 + lq;      // global query index
    const int W  = SWIN[0];      // sliding window (1024)

    const float scale = 0.125f;  // 1/sqrt(64)

    __shared__ float k_lds[TK * DD];
    __shared__ float v_lds[TK * DD];
    __shared__ float p_lds[TQ * (TK + 1)];
    __shared__ float red1[4 * TQ];
    __shared__ float red2[4 * TQ];

    const size_t basebh = (size_t)bh * S * DD;

    // ---- Q row -> registers (each of the 4 waves holds the same rows; L1 serves) ----
    float qreg[DD];
    {
        const float4* qp = (const float4*)(Q + basebh + (size_t)qi * DD);
        #pragma unroll
        for (int i = 0; i < DD / 4; ++i) {
            float4 f = qp[i];
            qreg[4*i+0] = f.x; qreg[4*i+1] = f.y;
            qreg[4*i+2] = f.z; qreg[4*i+3] = f.w;
        }
    }

    // ---- online-softmax state; sink folded into init ----
    float m = SINKW[h];
    float l = 1.0f;
    float acc[16];
    #pragma unroll
    for (int i = 0; i < 16; ++i) acc[i] = 0.0f;

    int lo = q0 - W; if (lo < 0) lo = 0;
    const int kt0 = lo / TK;
    const int kt1 = (q0 + TQ - 1) / TK;

    for (int kt = kt0; kt <= kt1; ++kt) {
        const int k0 = kt * TK;

        // protect previous iteration's p_lds/v_lds consumers
        __syncthreads();

        // ---- stage K,V tiles (coalesced float4 copies) ----
        {
            const float4* kp = (const float4*)(K + basebh + (size_t)k0 * DD);
            const float4* vp = (const float4*)(V + basebh + (size_t)k0 * DD);
            float4* kl = (float4*)k_lds;
            float4* vl = (float4*)v_lds;
            #pragma unroll
            for (int i = 0; i < (TK * DD / 4) / NT; ++i) {  // 4 iters
                kl[t + i * NT] = kp[t + i * NT];
                vl[t + i * NT] = vp[t + i * NT];
            }
        }
        __syncthreads();

        // ---- scores for this wave's 16 keys ----
        float s[16];
        float mloc = -1e30f;
        #pragma unroll
        for (int j = 0; j < 16; ++j) {
            const int n  = g * 16 + j;
            const int kk = k0 + n;
            float dot = 0.0f;
            const float4* kr = (const float4*)&k_lds[n * DD];  // broadcast reads
            #pragma unroll
            for (int d4 = 0; d4 < DD / 4; ++d4) {
                float4 f = kr[d4];
                dot += qreg[4*d4+0] * f.x + qreg[4*d4+1] * f.y
                     + qreg[4*d4+2] * f.z + qreg[4*d4+3] * f.w;
            }
            const bool valid = (kk <= qi) && (qi - kk <= W);
            s[j] = valid ? dot * scale : -1e30f;
            mloc = fmaxf(mloc, s[j]);
        }
        red1[g * TQ + lq] = mloc;
        __syncthreads();

        // ---- row max across the 4 waves; exp; partial sums ----
        const float mt = fmaxf(fmaxf(red1[0*TQ+lq], red1[1*TQ+lq]),
                               fmaxf(red1[2*TQ+lq], red1[3*TQ+lq]));
        const float mnew = fmaxf(m, mt);
        float psum = 0.0f;
        #pragma unroll
        for (int j = 0; j < 16; ++j) {
            const float p = __expf(s[j] - mnew);
            psum += p;
            p_lds[lq * (TK + 1) + g * 16 + j] = p;
        }
        red2[g * TQ + lq] = psum;
        __syncthreads();

        const float tsum = red2[0*TQ+lq] + red2[1*TQ+lq]
                         + red2[2*TQ+lq] + red2[3*TQ+lq];
        const float alpha = __expf(m - mnew);
        l = l * alpha + tsum;
        m = mnew;
        #pragma unroll
        for (int i = 0; i < 16; ++i) acc[i] *= alpha;

        // ---- PV: accumulate this wave's 16 dims over all 64 keys ----
        #pragma unroll 4
        for (int kk2 = 0; kk2 < TK; ++kk2) {
            const float p = p_lds[lq * (TK + 1) + kk2];          // stride-65: conflict-free
            const float4* vr = (const float4*)&v_lds[kk2 * DD + g * 16];  // broadcast
            #pragma unroll
            for (int d4 = 0; d4 < 4; ++d4) {
                float4 f = vr[d4];
                acc[4*d4+0] += p * f.x; acc[4*d4+1] += p * f.y;
                acc[4*d4+2] += p * f.z; acc[4*d4+3] += p * f.w;
            }
        }
    }

    // ---- epilogue: normalize and store ----
    const float inv = 1.0f / l;
    float4* op = (float4*)(OUT + basebh + (size_t)qi * DD + g * 16);
    #pragma unroll
    for (int d4 = 0; d4 < 4; ++d4) {
        float4 f;
        f.x = acc[4*d4+0] * inv; f.y = acc[4*d4+1] * inv;
        f.z = acc[4*d4+2] * inv; f.w = acc[4*d4+3] * inv;
        op[d4] = f;
    }
}

extern "C" void kernel_launch(void* const* d_in, const int* in_sizes, int n_in,
                              void* d_out, int out_size, void* d_ws, size_t ws_size,
                              hipStream_t stream) {
    const float* q     = (const float*)d_in[0];
    const float* k     = (const float*)d_in[1];
    const float* v     = (const float*)d_in[2];
    const float* sinkw = (const float*)d_in[3];
    const int*   swin  = (const int*)d_in[4];
    float* out = (float*)d_out;

    const int B = 2, S = 2048;
    const int H = in_sizes[3];          // 16 (sink_weights is [H])

    dim3 grid(S / TQ, B * H);
    flex_attn_fp32<<<grid, NT, 0, stream>>>(q, k, v, sinkw, swin, out, H, S);
}

// Round 2
// 164.644 us; speedup vs baseline: 2.9663x; 2.9663x over previous
//
#include <hip/hip_runtime.h>

// FlexAttention (sliding-window causal + per-head sink), MFMA bf16 flash kernel.
// B=2,H=16,S=2048,D=64,W=1024. grid=(32 q-tiles, 32 bh), block=256 (4 waves).
//
// Per block: 64-query tile. Per K-tile (64 keys):
//   stage K->LDS [key][dim] bf16 (stride 72), V->LDS transposed [dim][key]
//   wave g: QK^T rows [16g,16g+16) = 8 mfma_f32_16x16x32_bf16
//   softmax in registers (C-layout rows = quad*4+reg), sink: m0=sinkw, l0=1
//   P -> LDS (overlays k_lds) to convert C-layout -> A-layout
//   PV: 8 MFMAs vs V^T fragments.
// Layouts (measured, m89/m91/m120): A[m=lane&15][k=quad*8+j],
// B[k=quad*8+j][n=lane&15], C/D[row=quad*4+reg][col=lane&15].

typedef __bf16 bf16x8 __attribute__((ext_vector_type(8)));
typedef __bf16 bf16x4 __attribute__((ext_vector_type(4)));
typedef float  f32x4  __attribute__((ext_vector_type(4)));

#define TQ 64
#define TK 64
#define DD 64
#define SP 72          // LDS row stride (bf16 elems): 144B rows, 16B-aligned, bank-spread
#define NTHREADS 256

__global__ __launch_bounds__(NTHREADS, 4) void flex_attn_mfma(
    const float* __restrict__ Q, const float* __restrict__ K,
    const float* __restrict__ V, const float* __restrict__ SINKW,
    const int* __restrict__ SWIN, float* __restrict__ OUT,
    const int H, const int S)
{
    const int t    = threadIdx.x;
    const int l    = t & 63;
    const int g    = t >> 6;      // wave id: owns q-rows [16g, 16g+16)
    const int r    = l & 15;
    const int quad = l >> 4;
    const int qt   = blockIdx.x;
    const int bh   = blockIdx.y;
    const int h    = bh % H;
    const int q0   = qt * TQ;
    const int W    = SWIN[0];
    const float scale = 0.125f;   // 1/sqrt(64)

    __shared__ __align__(16) __bf16 kp_lds[TK * SP];  // K tile; reused for P
    __shared__ __align__(16) __bf16 vt_lds[DD * SP];  // V^T tile [dim][key]

    const size_t basebh = (size_t)bh * S * DD;

    // ---- persistent Q A-fragments (2 k-steps of 32 dims) ----
    bf16x8 aq[2];
    {
        const float* qp = Q + basebh + (size_t)(q0 + 16*g + r) * DD + quad * 8;
        #pragma unroll
        for (int ks = 0; ks < 2; ++ks)
            #pragma unroll
            for (int j = 0; j < 8; ++j)
                aq[ks][j] = (__bf16)qp[ks*32 + j];
    }

    // ---- online-softmax state; sink folded into init (m=sink, l=exp(0)=1) ----
    const float sw = SINKW[h];
    float mrow[4], lrow[4];
    f32x4 accO[4];
    #pragma unroll
    for (int i = 0; i < 4; ++i) {
        mrow[i] = sw; lrow[i] = 1.0f;
        accO[i].x = 0.f; accO[i].y = 0.f; accO[i].z = 0.f; accO[i].w = 0.f;
    }

    int lo = q0 - W; if (lo < 0) lo = 0;
    const int kt0 = lo >> 6;
    const int keyv = g * 16 + (l >> 2);   // V-staging key owned by this lane

    for (int kt = kt0; kt <= qt; ++kt) {
        const int k0 = kt * TK;
        __syncthreads();   // B1: prev-iter PV reads of kp/vt done before restage

        // ---- stage K tile -> kp_lds[key][dim] (coalesced f32x4 -> b64 writes) ----
        {
            const float4* kp = (const float4*)(K + basebh + (size_t)k0 * DD);
            #pragma unroll
            for (int i = 0; i < 4; ++i) {
                const int flat = i * NTHREADS + t;       // = key*16 + j
                float4 f = kp[flat];
                const int key = flat >> 4, j = flat & 15;
                bf16x4 b4 = { (__bf16)f.x, (__bf16)f.y, (__bf16)f.z, (__bf16)f.w };
                *(bf16x4*)&kp_lds[key * SP + j * 4] = b4;
            }
        }
        // ---- stage V tile transposed -> vt_lds[dim][key] ----
        // lane quad reads a 64B line (4 consecutive float4 of one key row)
        {
            const float4* vp = (const float4*)(V + basebh + (size_t)k0 * DD);
            #pragma unroll
            for (int i = 0; i < 4; ++i) {
                const int j = i * 4 + (l & 3);
                float4 f = vp[keyv * 16 + j];
                vt_lds[(4*j + 0) * SP + keyv] = (__bf16)f.x;
                vt_lds[(4*j + 1) * SP + keyv] = (__bf16)f.y;
                vt_lds[(4*j + 2) * SP + keyv] = (__bf16)f.z;
                vt_lds[(4*j + 3) * SP + keyv] = (__bf16)f.w;
            }
        }
        __syncthreads();   // B2: tiles visible

        // ---- QK^T: S[16 x 64] for this wave's rows ----
        f32x4 accS[4];
        #pragma unroll
        for (int nt = 0; nt < 4; ++nt) {
            accS[nt].x = 0.f; accS[nt].y = 0.f; accS[nt].z = 0.f; accS[nt].w = 0.f;
        }
        #pragma unroll
        for (int ks = 0; ks < 2; ++ks)
            #pragma unroll
            for (int nt = 0; nt < 4; ++nt) {
                bf16x8 bk = *(const bf16x8*)&kp_lds[(nt*16 + r) * SP + ks*32 + quad*8];
                accS[nt] = __builtin_amdgcn_mfma_f32_16x16x32_bf16(aq[ks], bk, accS[nt], 0, 0, 0);
            }

        // ---- mask + scale in C-layout ----
        #pragma unroll
        for (int nt = 0; nt < 4; ++nt)
            #pragma unroll
            for (int reg = 0; reg < 4; ++reg) {
                const int qi = q0 + 16*g + 4*quad + reg;
                const int ki = k0 + nt*16 + r;
                const bool valid = (ki <= qi) && (qi - ki <= W);
                accS[nt][reg] = valid ? accS[nt][reg] * scale : -1e30f;
            }

        // ---- online softmax (rows live in (quad,reg); cols across ntile x 16 lanes) ----
        float alpha[4];
        #pragma unroll
        for (int reg = 0; reg < 4; ++reg) {
            float mx = fmaxf(fmaxf(accS[0][reg], accS[1][reg]),
                             fmaxf(accS[2][reg], accS[3][reg]));
            #pragma unroll
            for (int d = 1; d < 16; d <<= 1) mx = fmaxf(mx, __shfl_xor(mx, d, 64));
            const float mnew = fmaxf(mrow[reg], mx);
            alpha[reg] = __expf(mrow[reg] - mnew);
            float ps = 0.f;
            #pragma unroll
            for (int nt = 0; nt < 4; ++nt) {
                const float p = __expf(accS[nt][reg] - mnew);
                accS[nt][reg] = p;       // reuse accS as P
                ps += p;
            }
            #pragma unroll
            for (int d = 1; d < 16; d <<= 1) ps += __shfl_xor(ps, d, 64);
            lrow[reg] = lrow[reg] * alpha[reg] + ps;
            mrow[reg] = mnew;
        }
        #pragma unroll
        for (int nt = 0; nt < 4; ++nt)
            #pragma unroll
            for (int reg = 0; reg < 4; ++reg)
                accO[nt][reg] *= alpha[reg];

        __syncthreads();   // B3: all waves done reading K before P overwrites kp_lds

        // ---- P (bf16) -> kp_lds rows [16g,16g+16): C-layout -> memory [q][key] ----
        #pragma unroll
        for (int nt = 0; nt < 4; ++nt)
            #pragma unroll
            for (int reg = 0; reg < 4; ++reg)
                kp_lds[(16*g + 4*quad + reg) * SP + nt*16 + r] = (__bf16)accS[nt][reg];

        __syncthreads();   // B4: P visible (cross-lane within wave still needs fence)

        // ---- PV: O[16 x 64] += P[16 x 64keys] * V[64keys x 64] ----
        #pragma unroll
        for (int ks = 0; ks < 2; ++ks) {
            bf16x8 ap = *(const bf16x8*)&kp_lds[(16*g + r) * SP + ks*32 + quad*8];
            #pragma unroll
            for (int nt = 0; nt < 4; ++nt) {
                bf16x8 bv = *(const bf16x8*)&vt_lds[(nt*16 + r) * SP + ks*32 + quad*8];
                accO[nt] = __builtin_amdgcn_mfma_f32_16x16x32_bf16(ap, bv, accO[nt], 0, 0, 0);
            }
        }
    }

    // ---- epilogue: normalize by l, store fp32 ----
    #pragma unroll
    for (int reg = 0; reg < 4; ++reg) {
        const float inv = 1.0f / lrow[reg];
        const int row = q0 + 16*g + 4*quad + reg;
        float* op = OUT + basebh + (size_t)row * DD + r;
        #pragma unroll
        for (int nt = 0; nt < 4; ++nt)
            op[nt * 16] = accO[nt][reg] * inv;
    }
}

extern "C" void kernel_launch(void* const* d_in, const int* in_sizes, int n_in,
                              void* d_out, int out_size, void* d_ws, size_t ws_size,
                              hipStream_t stream) {
    const float* q     = (const float*)d_in[0];
    const float* k     = (const float*)d_in[1];
    const float* v     = (const float*)d_in[2];
    const float* sinkw = (const float*)d_in[3];
    const int*   swin  = (const int*)d_in[4];
    float* out = (float*)d_out;

    const int H = in_sizes[3];            // 16
    const int S = 2048;
    const int B = in_sizes[0] / (H * S * DD);   // 2

    dim3 grid(S / TQ, B * H);
    flex_attn_mfma<<<grid, NTHREADS, 0, stream>>>(q, k, v, sinkw, swin, out, H, S);
}

// Round 3
// 147.744 us; speedup vs baseline: 3.3056x; 1.1144x over previous
//
#include <hip/hip_runtime.h>

// FlexAttention (sliding-window causal + per-head sink), R3: 32x32x16 MFMA,
// S^T formulation, software-pipelined staging.
// B=2,H=16,S=2048,D=64,W=1024. grid=(32 qt, 32 bh), block=128 (2 waves).
//
// Wave g owns q-rows [q0+32g, q0+32g+32). Per 64-key tile:
//   S^T = K(LDS)·Q^T(regs): 8 mfma_32x32x16. C-layout: col=q(lane&31),
//   row=key(reg-indexed) -> softmax is per-lane over 32 regs + 1 shfl_xor(32).
//   P stored [q][key] bf16: b64 writes (4 keys/reg-quad), b128 reads. Intra-wave.
//   O^T = V^T(LDS)·P^T: 8 mfma. O^T C-layout: col=q, row=dim -> float4 stores.
// Layouts (m74/m101 + 16x16 pattern): A[m=l&31][k=(l>>5)*8+j],
// B[k=(l>>5)*8+j][n=l&31], C/D[row=(reg&3)+8*(reg>>2)+4*(l>>5)][col=l&31].
// Pipeline: load tile kt+1 -> VGPRs during compute of kt; 2 barriers/tile
// bracket only the LDS staging writes.

typedef __bf16 bf16x8 __attribute__((ext_vector_type(8)));
typedef __bf16 bf16x4 __attribute__((ext_vector_type(4)));
typedef float  f32x16 __attribute__((ext_vector_type(16)));

#define SK 72
#define SV 72
#define SPP 72
#define NT 128

__global__ __launch_bounds__(NT, 2) void flex_attn_mfma32(
    const float* __restrict__ Q, const float* __restrict__ K,
    const float* __restrict__ V, const float* __restrict__ SINKW,
    const int* __restrict__ SWIN, float* __restrict__ OUT,
    const int H, const int S)
{
    const int t    = threadIdx.x;
    const int lane = t & 63;
    const int g    = t >> 6;        // wave id
    const int c    = lane & 31;     // column index (q within wave tile)
    const int hl   = lane >> 5;     // half-wave
    const int qt   = blockIdx.x;
    const int bh   = blockIdx.y;
    const int h    = bh % H;
    const int q0   = qt * 64;
    const int qw0  = q0 + 32 * g;
    const int W    = SWIN[0];
    const float scale = 0.125f;     // 1/sqrt(64)

    __shared__ __align__(16) __bf16 k_lds[64 * SK];      // K  [key][dim]
    __shared__ __align__(16) __bf16 v_lds[64 * SV];      // V^T [dim][key]
    __shared__ __align__(16) __bf16 p_lds[2 * 32 * SPP]; // per-wave P [q][key]

    const size_t basebh = (size_t)bh * S * 64;

    // ---- Q B-fragments (pre-scaled; stays in regs whole kernel) ----
    bf16x8 bq[4];
    {
        const float4* qp4 = (const float4*)(Q + basebh + (size_t)(qw0 + c) * 64);
        #pragma unroll
        for (int ks = 0; ks < 4; ++ks) {
            float4 f0 = qp4[4 * ks + 2 * hl];
            float4 f1 = qp4[4 * ks + 2 * hl + 1];
            bq[ks][0] = (__bf16)(f0.x * scale); bq[ks][1] = (__bf16)(f0.y * scale);
            bq[ks][2] = (__bf16)(f0.z * scale); bq[ks][3] = (__bf16)(f0.w * scale);
            bq[ks][4] = (__bf16)(f1.x * scale); bq[ks][5] = (__bf16)(f1.y * scale);
            bq[ks][6] = (__bf16)(f1.z * scale); bq[ks][7] = (__bf16)(f1.w * scale);
        }
    }

    // ---- staging decomposition ----
    const int dg = t & 15;          // V: dims 4dg..4dg+3
    const int kg = t >> 4;          // V: keys 4kg..4kg+3 (per 32-key round)
    const float4* kp4 = (const float4*)(K + basebh);
    const float4* vp4 = (const float4*)(V + basebh);
    float4 kreg[8], vreg[8];

    auto load_tiles = [&](int kt) {
        #pragma unroll
        for (int i = 0; i < 8; ++i)
            kreg[i] = kp4[kt * 1024 + i * NT + t];
        #pragma unroll
        for (int r = 0; r < 2; ++r)
            #pragma unroll
            for (int kk = 0; kk < 4; ++kk)
                vreg[4 * r + kk] = vp4[kt * 1024 + (32 * r + 4 * kg + kk) * 16 + dg];
    };

    auto stage_tiles = [&]() {
        #pragma unroll
        for (int i = 0; i < 8; ++i) {
            const int flat = i * NT + t;
            const int key = flat >> 4, dd = flat & 15;
            float4 f = kreg[i];
            bf16x4 b = { (__bf16)f.x, (__bf16)f.y, (__bf16)f.z, (__bf16)f.w };
            *(bf16x4*)&k_lds[key * SK + 4 * dd] = b;
        }
        #pragma unroll
        for (int r = 0; r < 2; ++r) {
            float4 a0 = vreg[4*r+0], a1 = vreg[4*r+1], a2 = vreg[4*r+2], a3 = vreg[4*r+3];
            const int kb = 32 * r + 4 * kg;
            bf16x4 w0 = { (__bf16)a0.x, (__bf16)a1.x, (__bf16)a2.x, (__bf16)a3.x };
            bf16x4 w1 = { (__bf16)a0.y, (__bf16)a1.y, (__bf16)a2.y, (__bf16)a3.y };
            bf16x4 w2 = { (__bf16)a0.z, (__bf16)a1.z, (__bf16)a2.z, (__bf16)a3.z };
            bf16x4 w3 = { (__bf16)a0.w, (__bf16)a1.w, (__bf16)a2.w, (__bf16)a3.w };
            *(bf16x4*)&v_lds[(4 * dg + 0) * SV + kb] = w0;
            *(bf16x4*)&v_lds[(4 * dg + 1) * SV + kb] = w1;
            *(bf16x4*)&v_lds[(4 * dg + 2) * SV + kb] = w2;
            *(bf16x4*)&v_lds[(4 * dg + 3) * SV + kb] = w3;
        }
    };

    // ---- online-softmax state: one (m,l) per lane (its q-column); sink folded in ----
    float mrun = SINKW[h];
    float lrun = 1.0f;
    f32x16 accO0, accO1;
    #pragma unroll
    for (int i = 0; i < 16; ++i) { accO0[i] = 0.0f; accO1[i] = 0.0f; }

    int lo = q0 - W; if (lo < 0) lo = 0;
    const int kt0 = lo >> 6, kt1 = qt;

    load_tiles(kt0);

    for (int kt = kt0; kt <= kt1; ++kt) {
        __syncthreads();            // B1: prev compute's LDS reads done
        stage_tiles();
        if (kt < kt1) load_tiles(kt + 1);   // hidden behind this tile's compute
        __syncthreads();            // B2: tiles visible

        const int k0 = kt * 64;

        // ---- S^T = K · Q^T ----
        f32x16 accS0, accS1;
        #pragma unroll
        for (int i = 0; i < 16; ++i) { accS0[i] = 0.0f; accS1[i] = 0.0f; }
        #pragma unroll
        for (int ks = 0; ks < 4; ++ks) {
            bf16x8 ka0 = *(const bf16x8*)&k_lds[c * SK + 16 * ks + 8 * hl];
            bf16x8 ka1 = *(const bf16x8*)&k_lds[(32 + c) * SK + 16 * ks + 8 * hl];
            accS0 = __builtin_amdgcn_mfma_f32_32x32x16_bf16(ka0, bq[ks], accS0, 0, 0, 0);
            accS1 = __builtin_amdgcn_mfma_f32_32x32x16_bf16(ka1, bq[ks], accS1, 0, 0, 0);
        }

        // ---- mask (skip for interior tiles; wave-uniform branch) ----
        const bool interior = (k0 + 63 <= qw0) && (qw0 + 31 - k0 <= W);
        if (!interior) {
            const int qi = qw0 + c;
            #pragma unroll
            for (int rg = 0; rg < 16; ++rg) {
                const int kb  = (rg & 3) + 8 * (rg >> 2) + 4 * hl;
                const int ki0 = k0 + kb, ki1 = k0 + 32 + kb;
                if (!((ki0 <= qi) && (qi - ki0 <= W))) accS0[rg] = -1e30f;
                if (!((ki1 <= qi) && (qi - ki1 <= W))) accS1[rg] = -1e30f;
            }
        }

        // ---- online softmax: per-lane over 32 regs + one half-wave exchange ----
        float mx = accS0[0];
        #pragma unroll
        for (int i = 1; i < 16; ++i) mx = fmaxf(mx, accS0[i]);
        #pragma unroll
        for (int i = 0; i < 16; ++i) mx = fmaxf(mx, accS1[i]);
        mx = fmaxf(mx, __shfl_xor(mx, 32, 64));
        const float mnew  = fmaxf(mrun, mx);
        const float alpha = __expf(mrun - mnew);
        float ps = 0.0f;
        #pragma unroll
        for (int i = 0; i < 16; ++i) { float p = __expf(accS0[i] - mnew); accS0[i] = p; ps += p; }
        #pragma unroll
        for (int i = 0; i < 16; ++i) { float p = __expf(accS1[i] - mnew); accS1[i] = p; ps += p; }
        ps += __shfl_xor(ps, 32, 64);
        lrun = lrun * alpha + ps;
        mrun = mnew;
        #pragma unroll
        for (int i = 0; i < 16; ++i) { accO0[i] *= alpha; accO1[i] *= alpha; }

        // ---- P -> LDS [q][key], b64 writes; intra-wave (no barrier) ----
        __bf16* pw = p_lds + g * 32 * SPP;
        #pragma unroll
        for (int rg = 0; rg < 4; ++rg) {
            bf16x4 b0 = { (__bf16)accS0[4*rg+0], (__bf16)accS0[4*rg+1],
                          (__bf16)accS0[4*rg+2], (__bf16)accS0[4*rg+3] };
            bf16x4 b1 = { (__bf16)accS1[4*rg+0], (__bf16)accS1[4*rg+1],
                          (__bf16)accS1[4*rg+2], (__bf16)accS1[4*rg+3] };
            *(bf16x4*)&pw[c * SPP +      8 * rg + 4 * hl] = b0;
            *(bf16x4*)&pw[c * SPP + 32 + 8 * rg + 4 * hl] = b1;
        }

        // ---- O^T += V^T · P^T ----
        #pragma unroll
        for (int ks = 0; ks < 4; ++ks) {
            bf16x8 bp  = *(const bf16x8*)&pw[c * SPP + 16 * ks + 8 * hl];
            bf16x8 va0 = *(const bf16x8*)&v_lds[c * SV + 16 * ks + 8 * hl];
            bf16x8 va1 = *(const bf16x8*)&v_lds[(32 + c) * SV + 16 * ks + 8 * hl];
            accO0 = __builtin_amdgcn_mfma_f32_32x32x16_bf16(va0, bp, accO0, 0, 0, 0);
            accO1 = __builtin_amdgcn_mfma_f32_32x32x16_bf16(va1, bp, accO1, 0, 0, 0);
        }
    }

    // ---- epilogue: O^T C-layout col=q -> per-lane scalar 1/l, float4 stores ----
    const float inv = 1.0f / lrun;
    float* ob = OUT + basebh + (size_t)(qw0 + c) * 64;
    #pragma unroll
    for (int rg = 0; rg < 4; ++rg) {
        float4 f0 = { accO0[4*rg+0]*inv, accO0[4*rg+1]*inv, accO0[4*rg+2]*inv, accO0[4*rg+3]*inv };
        float4 f1 = { accO1[4*rg+0]*inv, accO1[4*rg+1]*inv, accO1[4*rg+2]*inv, accO1[4*rg+3]*inv };
        *(float4*)&ob[     8 * rg + 4 * hl] = f0;
        *(float4*)&ob[32 + 8 * rg + 4 * hl] = f1;
    }
}

extern "C" void kernel_launch(void* const* d_in, const int* in_sizes, int n_in,
                              void* d_out, int out_size, void* d_ws, size_t ws_size,
                              hipStream_t stream) {
    const float* q     = (const float*)d_in[0];
    const float* k     = (const float*)d_in[1];
    const float* v     = (const float*)d_in[2];
    const float* sinkw = (const float*)d_in[3];
    const int*   swin  = (const int*)d_in[4];
    float* out = (float*)d_out;

    const int H = in_sizes[3];                   // 16
    const int S = 2048;
    const int B = in_sizes[0] / (H * S * 64);    // 2

    dim3 grid(S / 64, B * H);
    flex_attn_mfma32<<<grid, NT, 0, stream>>>(q, k, v, sinkw, swin, out, H, S);
}